// Round 8
// baseline (62.505 us; speedup 1.0000x reference)
//
#include <hip/hip_runtime.h>

typedef float f4 __attribute__((ext_vector_type(4)));

#define P   32   // parents per main block (R6-verified optimum; 128 regressed)
#define REC 36   // dwords per LDS record: 16B-aligned stride, banks spread by 4p

__device__ __forceinline__ unsigned int part1by2(unsigned int n) {
    n &= 1023u;
    n = (n ^ (n << 16)) & 0xFF0000FFu;
    n = (n ^ (n << 8))  & 0x0300F00Fu;
    n = (n ^ (n << 4))  & 0x030C30C3u;
    n = (n ^ (n << 2))  & 0x09249249u;
    return n;
}

// Grid role-split, morton blocks FIRST (co-reside with early main blocks):
//   blocks [0, mortonBlocks)           : morton codes, dense 2KB/wave stores
//   blocks [mortonBlocks, +mainBlocks) : out rows via LDS-staged records
__global__ __launch_bounds__(256) void asv_kernel(
    const float* __restrict__ positions,
    const float* __restrict__ sizes,
    const float* __restrict__ densities,
    const float* __restrict__ colors,
    const int*   __restrict__ level_p,
    float* __restrict__ out,
    float* __restrict__ morton_out,
    int N, int mortonBlocks)
{
    const int tid = threadIdx.x;

    if (blockIdx.x < mortonBlocks) {
        // ---------------- morton role: 1 parent per thread ----------------
        const int i = blockIdx.x * 256 + tid;
        if (i >= N) return;
        const int   gr  = 64 << level_p[0];
        const float grf = (float)gr;
        const float s  = sizes[i];
        const float t  = 0.25f * s;                    // exact pow2 scale
        const float px = positions[3 * i + 0];
        const float py = positions[3 * i + 1];
        const float pz = positions[3 * i + 2];

        // grid cell -> interleaved bits; only 2 distinct coords per axis
        #define CELL(c) ({                                                   \
            int _v = (int)(__fmul_rn(__fmul_rn(__fadd_rn((c), 1.0f), 0.5f), grf)); \
            _v = min(max(_v, 0), gr - 1);                                    \
            part1by2((unsigned)_v); })
        const unsigned bx0 = CELL(__fadd_rn(px, -t));
        const unsigned bx1 = CELL(__fadd_rn(px,  t));
        const unsigned by0 = CELL(__fadd_rn(py, -t)) << 1;
        const unsigned by1 = CELL(__fadd_rn(py,  t)) << 1;
        const unsigned bz0 = CELL(__fadd_rn(pz, -t)) << 2;
        const unsigned bz1 = CELL(__fadd_rn(pz,  t)) << 2;
        #undef CELL

        f4 m0 = {(float)(int)(bz0 | by0 | bx0), (float)(int)(bz0 | by0 | bx1),
                 (float)(int)(bz0 | by1 | bx0), (float)(int)(bz0 | by1 | bx1)};
        f4 m1 = {(float)(int)(bz1 | by0 | bx0), (float)(int)(bz1 | by0 | bx1),
                 (float)(int)(bz1 | by1 | bx0), (float)(int)(bz1 | by1 | bx1)};
        f4* mp = (f4*)(morton_out + (size_t)i * 8);
        __builtin_nontemporal_store(m0, mp);
        __builtin_nontemporal_store(m1, mp + 1);
        return;
    }

    // ---------------- main role: out rows via LDS-staged records ----------------
    __shared__ float rec[P * REC];
    const int mb   = blockIdx.x - mortonBlocks;
    const int base = mb * P;
    const int nloc = min(P, N - base);

    if (tid < nloc)
        rec[tid * REC + 3] = sizes[base + tid];
    if (tid >= 64 && tid < 64 + nloc)
        rec[(tid - 64) * REC + 4] = densities[base + (tid - 64)];
    if (tid >= 128 && tid < 128 + nloc * 3) {
        int k = tid - 128;
        rec[(k / 3) * REC + (k % 3)] = positions[(size_t)base * 3 + k];
    }
    // colors: 28MB read-once stream -> nontemporal (don't thrash L2;
    // pos/sizes stay cached since the morton role re-reads them)
    for (int k = tid; k < nloc * 27; k += 256)
        rec[(k / 27) * REC + 5 + (k % 27)] =
            __builtin_nontemporal_load(&colors[(size_t)base * 27 + k]);
    __syncthreads();

    const int kq = tid & 7;
    const int j  = (tid >> 3) & 7;                 // child index, loop-invariant
    const float sx = (j & 1) ? 0.25f : -0.25f;
    const float sy = (j & 2) ? 0.25f : -0.25f;
    const float sz = (j & 4) ? 0.25f : -0.25f;

    f4* __restrict__ outv = (f4*)out;
    const int qblock = mb * (P * 64);              // first quad of this block

    #pragma unroll
    for (int u = 0; u < 8; ++u) {
        const int lq = u * 256 + tid;              // local quad 0..2047
        const int p  = lq >> 6;                    // local parent
        if (p < nloc) {
            f4 v = *(const f4*)&rec[p * REC + kq * 4];
            if (kq == 0) {
                // match jnp rounding: off*size exact, then one rounded add
                f4 w = {__fadd_rn(v.x, sx * v.w),
                        __fadd_rn(v.y, sy * v.w),
                        __fadd_rn(v.z, sz * v.w),
                        0.5f * v.w};
                v = w;
            }
            __builtin_nontemporal_store(v, &outv[qblock + lq]);
        }
    }
}

extern "C" void kernel_launch(void* const* d_in, const int* in_sizes, int n_in,
                              void* d_out, int out_size, void* d_ws, size_t ws_size,
                              hipStream_t stream) {
    const float* positions = (const float*)d_in[0];
    const float* sizes     = (const float*)d_in[1];
    const float* densities = (const float*)d_in[2];
    const float* colors    = (const float*)d_in[3];
    const int*   level_p   = (const int*)d_in[4];

    int N = in_sizes[1];                           // sizes has N elements
    float* out        = (float*)d_out;
    float* morton_out = out + (size_t)N * 8 * 32;

    int mainBlocks   = (N + P - 1) / P;
    int mortonBlocks = (N + 255) / 256;
    asv_kernel<<<mortonBlocks + mainBlocks, 256, 0, stream>>>(
        positions, sizes, densities, colors, level_p, out, morton_out,
        N, mortonBlocks);
}

// Round 9
// 55.417 us; speedup vs baseline: 1.1279x; 1.1279x over previous
//
#include <hip/hip_runtime.h>

typedef float f4 __attribute__((ext_vector_type(4)));

#define P   32   // parents per main block (R6-verified optimum; 128 regressed)
#define REC 36   // dwords per LDS record: 16B-aligned stride, banks spread by 4p

__device__ __forceinline__ unsigned int part1by2(unsigned int n) {
    n &= 1023u;
    n = (n ^ (n << 16)) & 0xFF0000FFu;
    n = (n ^ (n << 8))  & 0x0300F00Fu;
    n = (n ^ (n << 4))  & 0x030C30C3u;
    n = (n ^ (n << 2))  & 0x09249249u;
    return n;
}

// Grid role-split, morton blocks FIRST (co-reside with early main blocks):
//   blocks [0, mortonBlocks)           : morton codes, dense 2KB/wave stores
//   blocks [mortonBlocks, +mainBlocks) : out rows via LDS-staged records
__global__ __launch_bounds__(256) void asv_kernel(
    const float* __restrict__ positions,
    const float* __restrict__ sizes,
    const float* __restrict__ densities,
    const float* __restrict__ colors,
    const int*   __restrict__ level_p,
    float* __restrict__ out,
    float* __restrict__ morton_out,
    int N, int mortonBlocks)
{
    const int tid = threadIdx.x;

    if (blockIdx.x < mortonBlocks) {
        // ---------------- morton role: 1 parent per thread ----------------
        const int i = blockIdx.x * 256 + tid;
        if (i >= N) return;
        const int   gr  = 64 << level_p[0];
        const float grf = (float)gr;
        const float s  = sizes[i];
        const float t  = 0.25f * s;                    // exact pow2 scale
        const float px = positions[3 * i + 0];
        const float py = positions[3 * i + 1];
        const float pz = positions[3 * i + 2];

        // grid cell -> interleaved bits; only 2 distinct coords per axis
        #define CELL(c) ({                                                   \
            int _v = (int)(__fmul_rn(__fmul_rn(__fadd_rn((c), 1.0f), 0.5f), grf)); \
            _v = min(max(_v, 0), gr - 1);                                    \
            part1by2((unsigned)_v); })
        const unsigned bx0 = CELL(__fadd_rn(px, -t));
        const unsigned bx1 = CELL(__fadd_rn(px,  t));
        const unsigned by0 = CELL(__fadd_rn(py, -t)) << 1;
        const unsigned by1 = CELL(__fadd_rn(py,  t)) << 1;
        const unsigned bz0 = CELL(__fadd_rn(pz, -t)) << 2;
        const unsigned bz1 = CELL(__fadd_rn(pz,  t)) << 2;
        #undef CELL

        f4 m0 = {(float)(int)(bz0 | by0 | bx0), (float)(int)(bz0 | by0 | bx1),
                 (float)(int)(bz0 | by1 | bx0), (float)(int)(bz0 | by1 | bx1)};
        f4 m1 = {(float)(int)(bz1 | by0 | bx0), (float)(int)(bz1 | by0 | bx1),
                 (float)(int)(bz1 | by1 | bx0), (float)(int)(bz1 | by1 | bx1)};
        f4* mp = (f4*)(morton_out + (size_t)i * 8);
        __builtin_nontemporal_store(m0, mp);
        __builtin_nontemporal_store(m1, mp + 1);
        return;
    }

    // ---------------- main role: out rows via LDS-staged records ----------------
    __shared__ float rec[P * REC];
    const int mb   = blockIdx.x - mortonBlocks;
    const int base = mb * P;
    const int nloc = min(P, N - base);

    if (tid < nloc)
        rec[tid * REC + 3] = sizes[base + tid];
    if (tid >= 64 && tid < 64 + nloc)
        rec[(tid - 64) * REC + 4] = densities[base + (tid - 64)];
    if (tid >= 128 && tid < 128 + nloc * 3) {
        int k = tid - 128;
        rec[(k / 3) * REC + (k % 3)] = positions[(size_t)base * 3 + k];
    }
    for (int k = tid; k < nloc * 27; k += 256)
        rec[(k / 27) * REC + 5 + (k % 27)] = colors[(size_t)base * 27 + k];
    __syncthreads();

    const int kq = tid & 7;
    const int j  = (tid >> 3) & 7;                 // child index, loop-invariant
    const float sx = (j & 1) ? 0.25f : -0.25f;
    const float sy = (j & 2) ? 0.25f : -0.25f;
    const float sz = (j & 4) ? 0.25f : -0.25f;

    f4* __restrict__ outv = (f4*)out;
    const int qblock = mb * (P * 64);              // first quad of this block

    #pragma unroll
    for (int u = 0; u < 8; ++u) {
        const int lq = u * 256 + tid;              // local quad 0..2047
        const int p  = lq >> 6;                    // local parent
        if (p < nloc) {
            f4 v = *(const f4*)&rec[p * REC + kq * 4];
            if (kq == 0) {
                // match jnp rounding: off*size exact, then one rounded add
                f4 w = {__fadd_rn(v.x, sx * v.w),
                        __fadd_rn(v.y, sy * v.w),
                        __fadd_rn(v.z, sz * v.w),
                        0.5f * v.w};
                v = w;
            }
            __builtin_nontemporal_store(v, &outv[qblock + lq]);
        }
    }
}

extern "C" void kernel_launch(void* const* d_in, const int* in_sizes, int n_in,
                              void* d_out, int out_size, void* d_ws, size_t ws_size,
                              hipStream_t stream) {
    const float* positions = (const float*)d_in[0];
    const float* sizes     = (const float*)d_in[1];
    const float* densities = (const float*)d_in[2];
    const float* colors    = (const float*)d_in[3];
    const int*   level_p   = (const int*)d_in[4];

    int N = in_sizes[1];                           // sizes has N elements
    float* out        = (float*)d_out;
    float* morton_out = out + (size_t)N * 8 * 32;

    int mainBlocks   = (N + P - 1) / P;
    int mortonBlocks = (N + 255) / 256;
    asv_kernel<<<mortonBlocks + mainBlocks, 256, 0, stream>>>(
        positions, sizes, densities, colors, level_p, out, morton_out,
        N, mortonBlocks);
}